// Round 12
// baseline (943.441 us; speedup 1.0000x reference)
//
#include <hip/hip_runtime.h>
#include <hip/hip_fp16.h>
#include <math.h>

#define N_NODES 100000
#define N_EDGES 3200000
#define SCAN_NB ((N_NODES + 255) / 256)   // 391

// Two-phase CSR build: 128 dst-range buckets, LDS-resident CSR assembly.
#define N_BKT 128
#define NPB 782                           // nodes per bucket (128*782 = 100096 >= N)
#define HALF_NPB 391
#define BKT_CHUNK 2000
#define BKT_NB (N_EDGES / BKT_CHUNK)      // 1600 blocks
#define BKT_LDS_CAP 64                    // per-bucket LDS staging (mean 15.6, P(ovfl)~1e-18)
#define BUCKET_CAP 26624                  // per-bucket region (mean 25000, +10 sigma)
#define SLICE_CAP 14336                   // LDS csr slice (mean 12512, +16 sigma)

// MLP pass A tiling: 64-node tile (grid 1563 -> ~6 blocks/CU; the 128-tile grid
// of 782 was occupancy-starved at ~3 blocks/CU), k staged in 4 chunks of <=33
#define TILE_NODES 64
#define KCH 33
#define MLP1_NB ((N_NODES + TILE_NODES - 1) / TILE_NODES)   // 1563

__device__ __forceinline__ unsigned int pack2(float a, float b) {
    __half2 h = __floats2half2_rn(a, b);
    return *reinterpret_cast<unsigned int*>(&h);
}
__device__ __forceinline__ float2 unpack2(unsigned int u) {
    __half2 h = *reinterpret_cast<__half2*>(&u);
    return __half22float2(h);
}

// ---------------- CSR build ----------------

__global__ void k_init(int* __restrict__ bcnt) {
    int i = threadIdx.x;
    if (i < N_BKT) bcnt[i] = 0;
}

// Phase 1: single coalesced pass over edges, pure bucketing (no global atomics).
// pack = (dst_local << 17) | src (dloc < 782 -> 10 bits, src < 100000 -> 17 bits).
__global__ __launch_bounds__(256) void k_bucket(
        const int* __restrict__ src, const int* __restrict__ dst,
        int* __restrict__ bcnt,
        unsigned int* __restrict__ bdata) {
    __shared__ unsigned int buf[N_BKT * BKT_LDS_CAP];   // 32768 B
    __shared__ int lcnt[N_BKT];
    __shared__ int gbase[N_BKT];
    const int t = threadIdx.x;
    if (t < N_BKT) lcnt[t] = 0;
    __syncthreads();

    const int e0 = blockIdx.x * BKT_CHUNK;
    for (int e = e0 + t; e < e0 + BKT_CHUNK; e += 256) {
        int d = __builtin_nontemporal_load(&dst[e]);
        int s = __builtin_nontemporal_load(&src[e]);
        int b = d / NPB;                              // magic-mul (const divisor)
        int dloc = d - b * NPB;
        unsigned int pack = ((unsigned int)dloc << 17) | (unsigned int)s;
        int p = atomicAdd(&lcnt[b], 1);               // LDS atomic
        if (p < BKT_LDS_CAP)                          // defensive clamp (never expected)
            buf[b * BKT_LDS_CAP + p] = pack;
    }
    __syncthreads();
    if (t < N_BKT) {
        int n = min(lcnt[t], BKT_LDS_CAP);
        lcnt[t] = n;
        gbase[t] = atomicAdd(&bcnt[t], n);
    }
    __syncthreads();
    const int wv = t >> 6, ln = t & 63;
    for (int b = wv; b < N_BKT; b += 4) {
        int n = lcnt[b];
        unsigned int* outp = bdata + (size_t)b * BUCKET_CAP + gbase[b];
        for (int i = ln; i < n; i += 64)
            __builtin_nontemporal_store(buf[b * BKT_LDS_CAP + i], &outp[i]);
    }
}

// Exclusive scan of the 128 bucket totals -> row_start of each bucket's first node.
__global__ __launch_bounds__(128) void k_bscan(const int* __restrict__ bcnt,
                                               int* __restrict__ bb) {
    __shared__ int s[128];
    const int t = threadIdx.x;
    int v = bcnt[t];
    s[t] = v;
    __syncthreads();
    for (int off = 1; off < 128; off <<= 1) {
        int a = (t >= off) ? s[t - off] : 0;
        __syncthreads();
        s[t] += a;
        __syncthreads();
    }
    bb[t] = s[t] - v;   // exclusive
    if (t == 127) bb[128] = s[127];
}

// Phase 2: LDS-resident CSR assembly + per-bucket degree derivation.
__global__ __launch_bounds__(512) void k_csr(
        const unsigned int* __restrict__ bdata,
        const int* __restrict__ bcnt,
        const int* __restrict__ bb,
        int* __restrict__ count,
        int* __restrict__ row_start,
        float* __restrict__ dinv,
        int* __restrict__ csr_src) {
    __shared__ int lhist[NPB];
    __shared__ int lrs[NPB];
    __shared__ int lcsr[SLICE_CAP];     // total LDS 63600 B
    const int b = blockIdx.x >> 1;
    const int half = blockIdx.x & 1;
    const int t = threadIdx.x;
    const int total = bcnt[b];
    const int bb_b = bb[b];
    const unsigned int* data = bdata + (size_t)b * BUCKET_CAP;

    for (int i = t; i < NPB; i += 512) lhist[i] = 0;
    __syncthreads();
    for (int i = t; i < total; i += 512) {
        unsigned int pack = __builtin_nontemporal_load(&data[i]);
        atomicAdd(&lhist[pack >> 17], 1);             // no-return LDS atomic
    }
    __syncthreads();
    // exclusive scan lhist -> lrs (wave 0: 13 elems/lane + shfl_up wave scan)
    if (t < 64) {
        int loc[13];
        int s = 0;
#pragma unroll
        for (int k = 0; k < 13; ++k) {
            int idx = t * 13 + k;
            int v = (idx < NPB) ? lhist[idx] : 0;
            loc[k] = v; s += v;
        }
        int run = s;
#pragma unroll
        for (int off = 1; off < 64; off <<= 1) {
            int o = __shfl_up(run, off, 64);
            if (t >= off) run += o;
        }
        int excl = run - s;
#pragma unroll
        for (int k = 0; k < 13; ++k) {
            int idx = t * 13 + k;
            if (idx < NPB) lrs[idx] = excl;
            excl += loc[k];
        }
    }
    __syncthreads();
    // per-node outputs for this half (coalesced)
    const int node_lo = b * NPB + half * HALF_NPB;
    int node_hi = b * NPB + (half ? NPB : HALF_NPB);
    if (node_hi > N_NODES) node_hi = N_NODES;
    const int nn = node_hi - node_lo;
    for (int i = t; i < nn; i += 512) {
        int dloc = half * HALF_NPB + i;
        int c = lhist[dloc];
        count[node_lo + i] = c;
        row_start[node_lo + i] = bb_b + lrs[dloc];
        dinv[node_lo + i] = 1.0f / sqrtf((float)(c + 1));   // deg incl self-loop
    }
    const int slice_off = lrs[half * HALF_NPB];
    const int slice_len = half ? (total - slice_off) : lrs[HALF_NPB];
    __syncthreads();   // lhist reads done -> safe to reuse as cursors
    const int dlo = half * HALF_NPB;
    const int dhi = dlo + HALF_NPB;
    for (int i = t; i < HALF_NPB; i += 512)
        lhist[dlo + i] = lrs[dlo + i] - slice_off;    // slice-local cursors
    __syncthreads();
    for (int i = t; i < total; i += 512) {
        unsigned int pack = __builtin_nontemporal_load(&data[i]);
        int dloc = (int)(pack >> 17);
        if (dloc >= dlo && dloc < dhi) {
            int p = atomicAdd(&lhist[dloc], 1);
            if (p < SLICE_CAP)                        // defensive clamp (never expected)
                lcsr[p] = (int)(pack & 0x1FFFFu);
        }
    }
    __syncthreads();
    const int gb = bb_b + slice_off;
    for (int i = t; i < slice_len; i += 512)
        __builtin_nontemporal_store(lcsr[i], &csr_src[gb + i]);
}

// ---------------- MLP pass A: layer 1 (131 -> 64) ----------------
// 64-node tile, 256 threads: wave-uniform quarter (t>>6) owns 16 of 64 outputs
// -> 16 accumulators/thread, VGPR stays low (NOT the R6 512-thread blowup).
// Grid 1563 -> ~6 blocks/CU co-resident (was 3 at the 128-tile), hiding the
// x staging latency. Output feature-major h1T[j][node], coalesced.

__global__ __launch_bounds__(256) void k_mlp1(
        const float* __restrict__ x,
        const float* __restrict__ W1, const float* __restrict__ b1,
        float* __restrict__ h1T) {
    __shared__ float xs[TILE_NODES * KCH];   // 8448 B
    const int t = threadIdx.x;
    const int nl = t & 63;
    const int q_u = __builtin_amdgcn_readfirstlane(t >> 6);  // wave-uniform quarter
    const int nbase = blockIdx.x * TILE_NODES;
    const int node = nbase + nl;

    float a[16];
#pragma unroll
    for (int j = 0; j < 16; ++j) a[j] = b1[q_u * 16 + j];

    for (int kc = 0; kc < 4; ++kc) {
        const int k0 = kc * KCH;
        const int len = (k0 + KCH <= 131) ? KCH : (131 - k0);   // 33,33,33,32
        __syncthreads();
        for (int i = t; i < TILE_NODES * KCH; i += 256) {
            int r = i / KCH;
            int c = i - r * KCH;
            int gr = nbase + r;
            xs[i] = (c < len && gr < N_NODES) ? x[(long)gr * 131 + k0 + c] : 0.0f;
        }
        __syncthreads();
        const float* myrow = xs + nl * KCH;
        for (int kk = 0; kk < len; ++kk) {
            float xk = myrow[kk];
            const float* wr = W1 + (k0 + kk) * 64 + q_u * 16;   // uniform -> s_load
#pragma unroll
            for (int j = 0; j < 16; ++j) a[j] += xk * wr[j];
        }
    }

    if (node < N_NODES) {
#pragma unroll
        for (int j = 0; j < 16; ++j)
            h1T[(q_u * 16 + j) * N_NODES + node] = tanhf(a[j]);
    }
}

// ---------------- MLP pass B: 64 -> 32 -> 16 -> conv-fuse ----------------
// Writes fp16 unified layout u16[node*8 + j] (8 x half2 = 32 B per node row;
// u16 total = 3.2 MB -> fits each XCD's 4 MB L2).

__global__ __launch_bounds__(256) void k_mlp2(
        const float* __restrict__ h1T,
        const float* __restrict__ W2, const float* __restrict__ b2,
        const float* __restrict__ W3, const float* __restrict__ b3,
        const float* __restrict__ Wc1,
        const float* __restrict__ dinv,
        unsigned int* __restrict__ u16) {
    const int node = blockIdx.x * 256 + threadIdx.x;
    if (node >= N_NODES) return;

    float a2[32];
#pragma unroll
    for (int j = 0; j < 32; ++j) a2[j] = b2[j];
    for (int k = 0; k < 64; ++k) {
        float hk = h1T[k * N_NODES + node];           // coalesced
        const float* wr = W2 + k * 32;                // uniform -> s_load
#pragma unroll
        for (int j = 0; j < 32; ++j) a2[j] += hk * wr[j];
    }
#pragma unroll
    for (int j = 0; j < 32; ++j) a2[j] = tanhf(a2[j]);

    float a3[16];
#pragma unroll
    for (int j = 0; j < 16; ++j) a3[j] = b3[j];
#pragma unroll 4
    for (int k = 0; k < 32; ++k) {
        float hk = a2[k];
        const float* wr = W3 + k * 16;
#pragma unroll
        for (int j = 0; j < 16; ++j) a3[j] += hk * wr[j];
    }

    float dv = dinv[node];
    float uo[16];
#pragma unroll
    for (int j = 0; j < 16; ++j) uo[j] = 0.0f;
#pragma unroll 4
    for (int k = 0; k < 16; ++k) {
        float hk = a3[k];
        const float* wr = Wc1 + k * 16;
#pragma unroll
        for (int j = 0; j < 16; ++j) uo[j] += hk * wr[j];
    }
    uint4* p = reinterpret_cast<uint4*>(u16 + (size_t)node * 8);
    uint4 w0, w1;
    w0.x = pack2(uo[0] * dv,  uo[1] * dv);  w0.y = pack2(uo[2] * dv,  uo[3] * dv);
    w0.z = pack2(uo[4] * dv,  uo[5] * dv);  w0.w = pack2(uo[6] * dv,  uo[7] * dv);
    w1.x = pack2(uo[8] * dv,  uo[9] * dv);  w1.y = pack2(uo[10] * dv, uo[11] * dv);
    w1.z = pack2(uo[12] * dv, uo[13] * dv); w1.w = pack2(uo[14] * dv, uo[15] * dv);
    p[0] = w0; p[1] = w1;
}

// ---------------- Fused aggregation + tanh + 16x16 transform (or classifier) ----------------
// fp16 u rows (32 B). 4 nodes/wave, 16 lanes/node: q = lp&1 (16 B half-row),
// g = lp>>1 (8 edge subgroups). All csr words issued up-front for cmax <= 64
// (covers max degree at this size); gathers fully unrolled. At ~58 us/launch
// this kernel sits at the divergent-request floor (~2 line-requests/edge
// through the TA pipe) -- left untouched this round.

__global__ __launch_bounds__(256) void k_agg(
        const unsigned int* __restrict__ u,
        const int* __restrict__ row_start,
        const int* __restrict__ count,
        const int* __restrict__ csr_src,
        const float* __restrict__ dinv,
        const float* __restrict__ bias,
        const float* __restrict__ W,      // 16x16 (mode 0) or 16x2 Wcls (mode 1)
        const float* __restrict__ bcls,   // mode 1 only
        unsigned int* __restrict__ u_next,// mode 0 output (fp16 rows)
        float* __restrict__ out,          // mode 1 output (fp32)
        int mode) {
    const int wave = threadIdx.x >> 6;
    const int lane = threadIdx.x & 63;
    const int lp = lane & 15;
    const int q = lp & 1;                              // 16B half-row slot
    const int q8 = q * 8;
    const int g = lp >> 1;                             // edge subgroup 0..7
    const int nb = lane >> 4;                          // node sub-index 0..3
    const int node = blockIdx.x * 16 + wave * 4 + nb;  // 6250*16 = 100000

    const int rs = row_start[node];
    const int cnt = count[node];
    const float dv = dinv[node];
    int cmax = cnt;
    cmax = max(cmax, __shfl_xor(cmax, 16, 64));
    cmax = max(cmax, __shfl_xor(cmax, 32, 64));        // wave-uniform loop bound

    float acc[8] = {0.0f, 0.0f, 0.0f, 0.0f, 0.0f, 0.0f, 0.0f, 0.0f};

    if (cmax <= 64) {
        // ---- deep-MLP path: all csr words issued up-front, gathers unrolled ----
        int idx[4];
#pragma unroll
        for (int c = 0; c < 4; ++c) {
            idx[c] = 0;
            if (c * 16 < cnt)                          // group-uniform guard
                idx[c] = __builtin_nontemporal_load(
                    &csr_src[min(rs + c * 16 + lp, N_EDGES - 1)]);
        }
#pragma unroll
        for (int c = 0; c < 4; ++c) {
#pragma unroll
            for (int r = 0; r < 2; ++r) {
                int e = c * 16 + 8 * r + g;
                int s = __shfl(idx[c], (lane & 48) + 8 * r + g, 64);
                if (e < cnt) {
                    const uint4 uv = *reinterpret_cast<const uint4*>(u + (size_t)s * 8 + q * 4);
                    float2 f0 = unpack2(uv.x), f1 = unpack2(uv.y);
                    float2 f2 = unpack2(uv.z), f3 = unpack2(uv.w);
                    acc[0] += f0.x; acc[1] += f0.y; acc[2] += f1.x; acc[3] += f1.y;
                    acc[4] += f2.x; acc[5] += f2.y; acc[6] += f3.x; acc[7] += f3.y;
                }
            }
        }
    } else {
        // ---- fallback (max degree > 64: never expected at this size) ----
        for (int base = 0; base < cmax; base += 16) {
            int idx0 = __builtin_nontemporal_load(
                &csr_src[min(rs + base + lp, N_EDGES - 1)]);
#pragma unroll
            for (int r = 0; r < 2; ++r) {
                int e = base + 8 * r + g;
                int s = __shfl(idx0, (lane & 48) + 8 * r + g, 64);
                if (e < cnt) {
                    const uint4 uv = *reinterpret_cast<const uint4*>(u + (size_t)s * 8 + q * 4);
                    float2 f0 = unpack2(uv.x), f1 = unpack2(uv.y);
                    float2 f2 = unpack2(uv.z), f3 = unpack2(uv.w);
                    acc[0] += f0.x; acc[1] += f0.y; acc[2] += f1.x; acc[3] += f1.y;
                    acc[4] += f2.x; acc[5] += f2.y; acc[6] += f3.x; acc[7] += f3.y;
                }
            }
        }
    }

    // reduce over the 8 edge subgroups (lane bits 1..3)
#pragma unroll
    for (int c = 0; c < 8; ++c) {
        acc[c] += __shfl_xor(acc[c], 2, 64);
        acc[c] += __shfl_xor(acc[c], 4, 64);
        acc[c] += __shfl_xor(acc[c], 8, 64);
    }
    // self-loop (u already dinv[src]-scaled)
    {
        const uint4 uv = *reinterpret_cast<const uint4*>(u + (size_t)node * 8 + q * 4);
        float2 f0 = unpack2(uv.x), f1 = unpack2(uv.y);
        float2 f2 = unpack2(uv.z), f3 = unpack2(uv.w);
        acc[0] += f0.x; acc[1] += f0.y; acc[2] += f1.x; acc[3] += f1.y;
        acc[4] += f2.x; acc[5] += f2.y; acc[6] += f3.x; acc[7] += f3.y;
    }

    float hn[8];
#pragma unroll
    for (int c = 0; c < 8; ++c)
        hn[c] = tanhf(dv * acc[c] + bias[q8 + c]);

    if (mode == 0) {
        float o[8] = {0.0f, 0.0f, 0.0f, 0.0f, 0.0f, 0.0f, 0.0f, 0.0f};
#pragma unroll
        for (int k = 0; k < 16; ++k) {
            // feature k lives in component k&7 of lane (lane&48)+(k>>3)  (q=k>>3, g=0)
            float hk = __shfl(hn[k & 7], (lane & 48) + (k >> 3), 64);
            const float* wrow = W + k * 16 + q8;      // 1 KB table, L1-hot
#pragma unroll
            for (int j = 0; j < 8; ++j) o[j] += hk * wrow[j];
        }
        if (g == 0) {
            uint4 w4;
            w4.x = pack2(dv * o[0], dv * o[1]); w4.y = pack2(dv * o[2], dv * o[3]);
            w4.z = pack2(dv * o[4], dv * o[5]); w4.w = pack2(dv * o[6], dv * o[7]);
            *reinterpret_cast<uint4*>(u_next + (size_t)node * 8 + q * 4) = w4;
        }
    } else {
        float p0 = 0.0f, p1 = 0.0f;
        if (g == 0) {
            float4 h4a, h4b;
            h4a.x = hn[0]; h4a.y = hn[1]; h4a.z = hn[2]; h4a.w = hn[3];
            h4b.x = hn[4]; h4b.y = hn[5]; h4b.z = hn[6]; h4b.w = hn[7];
            float4* ho = reinterpret_cast<float4*>(out + 200000 + (size_t)node * 16 + q8);
            ho[0] = h4a; ho[1] = h4b;
#pragma unroll
            for (int c = 0; c < 8; ++c) {
                p0 += hn[c] * W[(q8 + c) * 2 + 0];
                p1 += hn[c] * W[(q8 + c) * 2 + 1];
            }
        }
        p0 += __shfl_xor(p0, 1, 64);  p1 += __shfl_xor(p1, 1, 64);   // combine q halves
        if (lp == 0) {
            out[(long)node * 2 + 0] = p0 + bcls[0];
            out[(long)node * 2 + 1] = p1 + bcls[1];
        }
    }
}

// ---------------- launch ----------------

extern "C" void kernel_launch(void* const* d_in, const int* in_sizes, int n_in,
                              void* d_out, int out_size, void* d_ws, size_t ws_size,
                              hipStream_t stream) {
    const float* x    = (const float*)d_in[0];
    const int*   ei   = (const int*)d_in[1];
    const float* W1   = (const float*)d_in[2];
    const float* b1   = (const float*)d_in[3];
    const float* W2   = (const float*)d_in[4];
    const float* b2   = (const float*)d_in[5];
    const float* W3   = (const float*)d_in[6];
    const float* b3   = (const float*)d_in[7];
    const float* Wc1  = (const float*)d_in[8];
    const float* bc1  = (const float*)d_in[9];
    const float* Wg   = (const float*)d_in[10];
    const float* bg   = (const float*)d_in[11];
    const float* Wcls = (const float*)d_in[12];
    const float* bcls = (const float*)d_in[13];
    float* out = (float*)d_out;

    const int* src = ei;
    const int* dst = ei + N_EDGES;

    int* count     = (int*)d_ws;
    int* row_start = count + N_NODES;
    float* dinv    = (float*)(row_start + N_NODES);
    int* bcnt      = (int*)(dinv + N_NODES);        // 128 ints
    int* bb        = bcnt + N_BKT;                  // 129 ints (padded to 132)
    int* csr_src   = bb + 132;
    unsigned int* u0 = (unsigned int*)(csr_src + N_EDGES);  // N*8 u32 (3.2 MB), 16B-aligned
    unsigned int* u1 = u0 + 8 * N_NODES;            // N*8 u32
    float* h1T     = (float*)(u1 + 8 * N_NODES);    // 64 * N floats (25.6 MB)
    unsigned int* bdata = (unsigned int*)h1T;       // 13.6 MB, dead before k_mlp1 writes h1T

    k_init<<<1, 128, 0, stream>>>(bcnt);
    k_bucket<<<BKT_NB, 256, 0, stream>>>(src, dst, bcnt, bdata);
    k_bscan<<<1, 128, 0, stream>>>(bcnt, bb);
    k_csr<<<2 * N_BKT, 512, 0, stream>>>(bdata, bcnt, bb, count, row_start, dinv, csr_src);
    k_mlp1<<<MLP1_NB, 256, 0, stream>>>(x, W1, b1, h1T);
    k_mlp2<<<SCAN_NB, 256, 0, stream>>>(h1T, W2, b2, W3, b3, Wc1, dinv, u0);

    unsigned int* ucur = u0;
    unsigned int* unxt = u1;
    for (int j = 0; j < 10; ++j) {
        const float* bias = (j < 5) ? bc1 : (bg + (long)(j - 5) * 16);
        if (j < 9) {
            const float* Wn = (j < 4) ? Wc1 : (Wg + (long)(j - 4) * 256);
            k_agg<<<6250, 256, 0, stream>>>(ucur, row_start, count, csr_src, dinv,
                                            bias, Wn, nullptr, unxt, nullptr, 0);
            unsigned int* tmp = ucur; ucur = unxt; unxt = tmp;
        } else {
            k_agg<<<6250, 256, 0, stream>>>(ucur, row_start, count, csr_src, dinv,
                                            bias, Wcls, bcls, nullptr, out, 1);
        }
    }
}

// Round 13
// 787.219 us; speedup vs baseline: 1.1984x; 1.1984x over previous
//
#include <hip/hip_runtime.h>
#include <hip/hip_fp16.h>
#include <math.h>

#define N_NODES 100000
#define N_EDGES 3200000
#define SCAN_NB ((N_NODES + 255) / 256)   // 391

// Two-phase CSR build: 128 dst-range buckets, LDS-resident CSR assembly.
#define N_BKT 128
#define NPB 782                           // nodes per bucket (128*782 = 100096 >= N)
#define HALF_NPB 391
#define BKT_CHUNK 2000
#define BKT_NB (N_EDGES / BKT_CHUNK)      // 1600 blocks
#define BKT_LDS_CAP 64                    // per-bucket LDS staging (mean 15.6, P(ovfl)~1e-18)
#define BUCKET_CAP 26624                  // per-bucket region (mean 25000, +10 sigma)
#define SLICE_CAP 14336                   // LDS csr slice (mean 12512, +16 sigma)

// MLP pass A tiling: 128-node tile, k staged in 4 chunks of <=33.
// FROZEN: 256 threads / 32 accumulators / wave-uniform half (t>>7). Two
// attempts to reshape this loop (512t R6, 64-tile R12) both broke codegen
// (VGPR blowup / per-lane W addressing) and ran 3.5x slower. Do not touch.
#define TILE_NODES 128
#define KCH 33
#define MLP1_NB ((N_NODES + TILE_NODES - 1) / TILE_NODES)   // 782

__device__ __forceinline__ unsigned int pack2(float a, float b) {
    __half2 h = __floats2half2_rn(a, b);
    return *reinterpret_cast<unsigned int*>(&h);
}
__device__ __forceinline__ float2 unpack2(unsigned int u) {
    __half2 h = *reinterpret_cast<__half2*>(&u);
    return __half22float2(h);
}

// ---------------- CSR build ----------------

__global__ void k_init(int* __restrict__ bcnt) {
    int i = threadIdx.x;
    if (i < N_BKT) bcnt[i] = 0;
}

// Phase 1: single coalesced pass over edges, pure bucketing (no global atomics).
// pack = (dst_local << 17) | src (dloc < 782 -> 10 bits, src < 100000 -> 17 bits).
__global__ __launch_bounds__(256) void k_bucket(
        const int* __restrict__ src, const int* __restrict__ dst,
        int* __restrict__ bcnt,
        unsigned int* __restrict__ bdata) {
    __shared__ unsigned int buf[N_BKT * BKT_LDS_CAP];   // 32768 B
    __shared__ int lcnt[N_BKT];
    __shared__ int gbase[N_BKT];
    const int t = threadIdx.x;
    if (t < N_BKT) lcnt[t] = 0;
    __syncthreads();

    const int e0 = blockIdx.x * BKT_CHUNK;
    for (int e = e0 + t; e < e0 + BKT_CHUNK; e += 256) {
        int d = __builtin_nontemporal_load(&dst[e]);
        int s = __builtin_nontemporal_load(&src[e]);
        int b = d / NPB;                              // magic-mul (const divisor)
        int dloc = d - b * NPB;
        unsigned int pack = ((unsigned int)dloc << 17) | (unsigned int)s;
        int p = atomicAdd(&lcnt[b], 1);               // LDS atomic
        if (p < BKT_LDS_CAP)                          // defensive clamp (never expected)
            buf[b * BKT_LDS_CAP + p] = pack;
    }
    __syncthreads();
    if (t < N_BKT) {
        int n = min(lcnt[t], BKT_LDS_CAP);
        lcnt[t] = n;
        gbase[t] = atomicAdd(&bcnt[t], n);
    }
    __syncthreads();
    const int wv = t >> 6, ln = t & 63;
    for (int b = wv; b < N_BKT; b += 4) {
        int n = lcnt[b];
        unsigned int* outp = bdata + (size_t)b * BUCKET_CAP + gbase[b];
        for (int i = ln; i < n; i += 64)
            __builtin_nontemporal_store(buf[b * BKT_LDS_CAP + i], &outp[i]);
    }
}

// Exclusive scan of the 128 bucket totals -> row_start of each bucket's first node.
__global__ __launch_bounds__(128) void k_bscan(const int* __restrict__ bcnt,
                                               int* __restrict__ bb) {
    __shared__ int s[128];
    const int t = threadIdx.x;
    int v = bcnt[t];
    s[t] = v;
    __syncthreads();
    for (int off = 1; off < 128; off <<= 1) {
        int a = (t >= off) ? s[t - off] : 0;
        __syncthreads();
        s[t] += a;
        __syncthreads();
    }
    bb[t] = s[t] - v;   // exclusive
    if (t == 127) bb[128] = s[127];
}

// Phase 2: LDS-resident CSR assembly + per-bucket degree derivation.
__global__ __launch_bounds__(512) void k_csr(
        const unsigned int* __restrict__ bdata,
        const int* __restrict__ bcnt,
        const int* __restrict__ bb,
        int* __restrict__ count,
        int* __restrict__ row_start,
        float* __restrict__ dinv,
        int* __restrict__ csr_src) {
    __shared__ int lhist[NPB];
    __shared__ int lrs[NPB];
    __shared__ int lcsr[SLICE_CAP];     // total LDS 63600 B
    const int b = blockIdx.x >> 1;
    const int half = blockIdx.x & 1;
    const int t = threadIdx.x;
    const int total = bcnt[b];
    const int bb_b = bb[b];
    const unsigned int* data = bdata + (size_t)b * BUCKET_CAP;

    for (int i = t; i < NPB; i += 512) lhist[i] = 0;
    __syncthreads();
    for (int i = t; i < total; i += 512) {
        unsigned int pack = __builtin_nontemporal_load(&data[i]);
        atomicAdd(&lhist[pack >> 17], 1);             // no-return LDS atomic
    }
    __syncthreads();
    // exclusive scan lhist -> lrs (wave 0: 13 elems/lane + shfl_up wave scan)
    if (t < 64) {
        int loc[13];
        int s = 0;
#pragma unroll
        for (int k = 0; k < 13; ++k) {
            int idx = t * 13 + k;
            int v = (idx < NPB) ? lhist[idx] : 0;
            loc[k] = v; s += v;
        }
        int run = s;
#pragma unroll
        for (int off = 1; off < 64; off <<= 1) {
            int o = __shfl_up(run, off, 64);
            if (t >= off) run += o;
        }
        int excl = run - s;
#pragma unroll
        for (int k = 0; k < 13; ++k) {
            int idx = t * 13 + k;
            if (idx < NPB) lrs[idx] = excl;
            excl += loc[k];
        }
    }
    __syncthreads();
    // per-node outputs for this half (coalesced)
    const int node_lo = b * NPB + half * HALF_NPB;
    int node_hi = b * NPB + (half ? NPB : HALF_NPB);
    if (node_hi > N_NODES) node_hi = N_NODES;
    const int nn = node_hi - node_lo;
    for (int i = t; i < nn; i += 512) {
        int dloc = half * HALF_NPB + i;
        int c = lhist[dloc];
        count[node_lo + i] = c;
        row_start[node_lo + i] = bb_b + lrs[dloc];
        dinv[node_lo + i] = 1.0f / sqrtf((float)(c + 1));   // deg incl self-loop
    }
    const int slice_off = lrs[half * HALF_NPB];
    const int slice_len = half ? (total - slice_off) : lrs[HALF_NPB];
    __syncthreads();   // lhist reads done -> safe to reuse as cursors
    const int dlo = half * HALF_NPB;
    const int dhi = dlo + HALF_NPB;
    for (int i = t; i < HALF_NPB; i += 512)
        lhist[dlo + i] = lrs[dlo + i] - slice_off;    // slice-local cursors
    __syncthreads();
    for (int i = t; i < total; i += 512) {
        unsigned int pack = __builtin_nontemporal_load(&data[i]);
        int dloc = (int)(pack >> 17);
        if (dloc >= dlo && dloc < dhi) {
            int p = atomicAdd(&lhist[dloc], 1);
            if (p < SLICE_CAP)                        // defensive clamp (never expected)
                lcsr[p] = (int)(pack & 0x1FFFFu);
        }
    }
    __syncthreads();
    const int gb = bb_b + slice_off;
    for (int i = t; i < slice_len; i += 512)
        __builtin_nontemporal_store(lcsr[i], &csr_src[gb + i]);
}

// ---------------- MLP pass A: layer 1 (131 -> 64) ----------------
// Proven 256-thread / 32-accumulator form (67 us, VGPR 24). Thread half (t>>7,
// wave-uniform) owns 32 of 64 outputs. Output feature-major h1T, coalesced.

__global__ __launch_bounds__(256) void k_mlp1(
        const float* __restrict__ x,
        const float* __restrict__ W1, const float* __restrict__ b1,
        float* __restrict__ h1T) {
    __shared__ float xs[TILE_NODES * KCH];   // 16896 B
    const int t = threadIdx.x;
    const int nl = t & 127;
    const int half_u = __builtin_amdgcn_readfirstlane(t >> 7);  // wave-uniform
    const int nbase = blockIdx.x * TILE_NODES;
    const int node = nbase + nl;

    float a[32];
#pragma unroll
    for (int j = 0; j < 32; ++j) a[j] = b1[half_u * 32 + j];

    for (int kc = 0; kc < 4; ++kc) {
        const int k0 = kc * KCH;
        const int len = (k0 + KCH <= 131) ? KCH : (131 - k0);   // 33,33,33,32
        __syncthreads();
        for (int i = t; i < TILE_NODES * KCH; i += 256) {
            int r = i / KCH;
            int c = i - r * KCH;
            int gr = nbase + r;
            xs[i] = (c < len && gr < N_NODES) ? x[(long)gr * 131 + k0 + c] : 0.0f;
        }
        __syncthreads();
        const float* myrow = xs + nl * KCH;
        for (int kk = 0; kk < len; ++kk) {
            float xk = myrow[kk];
            const float* wr = W1 + (k0 + kk) * 64 + half_u * 32;   // uniform -> s_load
#pragma unroll
            for (int j = 0; j < 32; ++j) a[j] += xk * wr[j];
        }
    }

    if (node < N_NODES) {
#pragma unroll
        for (int j = 0; j < 32; ++j)
            h1T[(half_u * 32 + j) * N_NODES + node] = tanhf(a[j]);
    }
}

// ---------------- MLP pass B: 64 -> 32 -> 16 -> conv-fuse ----------------
// Writes fp16 unified layout u16[node*8 + j] (8 x half2 = 32 B per node row;
// u16 total = 3.2 MB -> fits each XCD's 4 MB L2).

__global__ __launch_bounds__(256) void k_mlp2(
        const float* __restrict__ h1T,
        const float* __restrict__ W2, const float* __restrict__ b2,
        const float* __restrict__ W3, const float* __restrict__ b3,
        const float* __restrict__ Wc1,
        const float* __restrict__ dinv,
        unsigned int* __restrict__ u16) {
    const int node = blockIdx.x * 256 + threadIdx.x;
    if (node >= N_NODES) return;

    float a2[32];
#pragma unroll
    for (int j = 0; j < 32; ++j) a2[j] = b2[j];
    for (int k = 0; k < 64; ++k) {
        float hk = h1T[k * N_NODES + node];           // coalesced
        const float* wr = W2 + k * 32;                // uniform -> s_load
#pragma unroll
        for (int j = 0; j < 32; ++j) a2[j] += hk * wr[j];
    }
#pragma unroll
    for (int j = 0; j < 32; ++j) a2[j] = tanhf(a2[j]);

    float a3[16];
#pragma unroll
    for (int j = 0; j < 16; ++j) a3[j] = b3[j];
#pragma unroll 4
    for (int k = 0; k < 32; ++k) {
        float hk = a2[k];
        const float* wr = W3 + k * 16;
#pragma unroll
        for (int j = 0; j < 16; ++j) a3[j] += hk * wr[j];
    }

    float dv = dinv[node];
    float uo[16];
#pragma unroll
    for (int j = 0; j < 16; ++j) uo[j] = 0.0f;
#pragma unroll 4
    for (int k = 0; k < 16; ++k) {
        float hk = a3[k];
        const float* wr = Wc1 + k * 16;
#pragma unroll
        for (int j = 0; j < 16; ++j) uo[j] += hk * wr[j];
    }
    uint4* p = reinterpret_cast<uint4*>(u16 + (size_t)node * 8);
    uint4 w0, w1;
    w0.x = pack2(uo[0] * dv,  uo[1] * dv);  w0.y = pack2(uo[2] * dv,  uo[3] * dv);
    w0.z = pack2(uo[4] * dv,  uo[5] * dv);  w0.w = pack2(uo[6] * dv,  uo[7] * dv);
    w1.x = pack2(uo[8] * dv,  uo[9] * dv);  w1.y = pack2(uo[10] * dv, uo[11] * dv);
    w1.z = pack2(uo[12] * dv, uo[13] * dv); w1.w = pack2(uo[14] * dv, uo[15] * dv);
    p[0] = w0; p[1] = w1;
}

// ---------------- Fused aggregation + tanh + 16x16 transform (or classifier) ----------------
// fp16 u rows (32 B). 4 nodes/wave, 16 lanes/node: q = lp&1 (16 B half-row),
// g = lp>>1 (8 edge subgroups). All csr words issued up-front for cmax <= 64
// (covers max degree at this size); gathers fully unrolled. At ~58 us/launch
// this kernel sits at the divergent-request concurrency floor (~2 L1-missing
// lane-requests/edge against the per-CU outstanding-miss cap) — R4/R7/R10/R11
// schedule variants all converge here. Frozen.

__global__ __launch_bounds__(256) void k_agg(
        const unsigned int* __restrict__ u,
        const int* __restrict__ row_start,
        const int* __restrict__ count,
        const int* __restrict__ csr_src,
        const float* __restrict__ dinv,
        const float* __restrict__ bias,
        const float* __restrict__ W,      // 16x16 (mode 0) or 16x2 Wcls (mode 1)
        const float* __restrict__ bcls,   // mode 1 only
        unsigned int* __restrict__ u_next,// mode 0 output (fp16 rows)
        float* __restrict__ out,          // mode 1 output (fp32)
        int mode) {
    const int wave = threadIdx.x >> 6;
    const int lane = threadIdx.x & 63;
    const int lp = lane & 15;
    const int q = lp & 1;                              // 16B half-row slot
    const int q8 = q * 8;
    const int g = lp >> 1;                             // edge subgroup 0..7
    const int nb = lane >> 4;                          // node sub-index 0..3
    const int node = blockIdx.x * 16 + wave * 4 + nb;  // 6250*16 = 100000

    const int rs = row_start[node];
    const int cnt = count[node];
    const float dv = dinv[node];
    int cmax = cnt;
    cmax = max(cmax, __shfl_xor(cmax, 16, 64));
    cmax = max(cmax, __shfl_xor(cmax, 32, 64));        // wave-uniform loop bound

    float acc[8] = {0.0f, 0.0f, 0.0f, 0.0f, 0.0f, 0.0f, 0.0f, 0.0f};

    if (cmax <= 64) {
        // ---- deep-MLP path: all csr words issued up-front, gathers unrolled ----
        int idx[4];
#pragma unroll
        for (int c = 0; c < 4; ++c) {
            idx[c] = 0;
            if (c * 16 < cnt)                          // group-uniform guard
                idx[c] = __builtin_nontemporal_load(
                    &csr_src[min(rs + c * 16 + lp, N_EDGES - 1)]);
        }
#pragma unroll
        for (int c = 0; c < 4; ++c) {
#pragma unroll
            for (int r = 0; r < 2; ++r) {
                int e = c * 16 + 8 * r + g;
                int s = __shfl(idx[c], (lane & 48) + 8 * r + g, 64);
                if (e < cnt) {
                    const uint4 uv = *reinterpret_cast<const uint4*>(u + (size_t)s * 8 + q * 4);
                    float2 f0 = unpack2(uv.x), f1 = unpack2(uv.y);
                    float2 f2 = unpack2(uv.z), f3 = unpack2(uv.w);
                    acc[0] += f0.x; acc[1] += f0.y; acc[2] += f1.x; acc[3] += f1.y;
                    acc[4] += f2.x; acc[5] += f2.y; acc[6] += f3.x; acc[7] += f3.y;
                }
            }
        }
    } else {
        // ---- fallback (max degree > 64: never expected at this size) ----
        for (int base = 0; base < cmax; base += 16) {
            int idx0 = __builtin_nontemporal_load(
                &csr_src[min(rs + base + lp, N_EDGES - 1)]);
#pragma unroll
            for (int r = 0; r < 2; ++r) {
                int e = base + 8 * r + g;
                int s = __shfl(idx0, (lane & 48) + 8 * r + g, 64);
                if (e < cnt) {
                    const uint4 uv = *reinterpret_cast<const uint4*>(u + (size_t)s * 8 + q * 4);
                    float2 f0 = unpack2(uv.x), f1 = unpack2(uv.y);
                    float2 f2 = unpack2(uv.z), f3 = unpack2(uv.w);
                    acc[0] += f0.x; acc[1] += f0.y; acc[2] += f1.x; acc[3] += f1.y;
                    acc[4] += f2.x; acc[5] += f2.y; acc[6] += f3.x; acc[7] += f3.y;
                }
            }
        }
    }

    // reduce over the 8 edge subgroups (lane bits 1..3)
#pragma unroll
    for (int c = 0; c < 8; ++c) {
        acc[c] += __shfl_xor(acc[c], 2, 64);
        acc[c] += __shfl_xor(acc[c], 4, 64);
        acc[c] += __shfl_xor(acc[c], 8, 64);
    }
    // self-loop (u already dinv[src]-scaled)
    {
        const uint4 uv = *reinterpret_cast<const uint4*>(u + (size_t)node * 8 + q * 4);
        float2 f0 = unpack2(uv.x), f1 = unpack2(uv.y);
        float2 f2 = unpack2(uv.z), f3 = unpack2(uv.w);
        acc[0] += f0.x; acc[1] += f0.y; acc[2] += f1.x; acc[3] += f1.y;
        acc[4] += f2.x; acc[5] += f2.y; acc[6] += f3.x; acc[7] += f3.y;
    }

    float hn[8];
#pragma unroll
    for (int c = 0; c < 8; ++c)
        hn[c] = tanhf(dv * acc[c] + bias[q8 + c]);

    if (mode == 0) {
        float o[8] = {0.0f, 0.0f, 0.0f, 0.0f, 0.0f, 0.0f, 0.0f, 0.0f};
#pragma unroll
        for (int k = 0; k < 16; ++k) {
            // feature k lives in component k&7 of lane (lane&48)+(k>>3)  (q=k>>3, g=0)
            float hk = __shfl(hn[k & 7], (lane & 48) + (k >> 3), 64);
            const float* wrow = W + k * 16 + q8;      // 1 KB table, L1-hot
#pragma unroll
            for (int j = 0; j < 8; ++j) o[j] += hk * wrow[j];
        }
        if (g == 0) {
            uint4 w4;
            w4.x = pack2(dv * o[0], dv * o[1]); w4.y = pack2(dv * o[2], dv * o[3]);
            w4.z = pack2(dv * o[4], dv * o[5]); w4.w = pack2(dv * o[6], dv * o[7]);
            *reinterpret_cast<uint4*>(u_next + (size_t)node * 8 + q * 4) = w4;
        }
    } else {
        float p0 = 0.0f, p1 = 0.0f;
        if (g == 0) {
            float4 h4a, h4b;
            h4a.x = hn[0]; h4a.y = hn[1]; h4a.z = hn[2]; h4a.w = hn[3];
            h4b.x = hn[4]; h4b.y = hn[5]; h4b.z = hn[6]; h4b.w = hn[7];
            float4* ho = reinterpret_cast<float4*>(out + 200000 + (size_t)node * 16 + q8);
            ho[0] = h4a; ho[1] = h4b;
#pragma unroll
            for (int c = 0; c < 8; ++c) {
                p0 += hn[c] * W[(q8 + c) * 2 + 0];
                p1 += hn[c] * W[(q8 + c) * 2 + 1];
            }
        }
        p0 += __shfl_xor(p0, 1, 64);  p1 += __shfl_xor(p1, 1, 64);   // combine q halves
        if (lp == 0) {
            out[(long)node * 2 + 0] = p0 + bcls[0];
            out[(long)node * 2 + 1] = p1 + bcls[1];
        }
    }
}

// ---------------- launch ----------------

extern "C" void kernel_launch(void* const* d_in, const int* in_sizes, int n_in,
                              void* d_out, int out_size, void* d_ws, size_t ws_size,
                              hipStream_t stream) {
    const float* x    = (const float*)d_in[0];
    const int*   ei   = (const int*)d_in[1];
    const float* W1   = (const float*)d_in[2];
    const float* b1   = (const float*)d_in[3];
    const float* W2   = (const float*)d_in[4];
    const float* b2   = (const float*)d_in[5];
    const float* W3   = (const float*)d_in[6];
    const float* b3   = (const float*)d_in[7];
    const float* Wc1  = (const float*)d_in[8];
    const float* bc1  = (const float*)d_in[9];
    const float* Wg   = (const float*)d_in[10];
    const float* bg   = (const float*)d_in[11];
    const float* Wcls = (const float*)d_in[12];
    const float* bcls = (const float*)d_in[13];
    float* out = (float*)d_out;

    const int* src = ei;
    const int* dst = ei + N_EDGES;

    int* count     = (int*)d_ws;
    int* row_start = count + N_NODES;
    float* dinv    = (float*)(row_start + N_NODES);
    int* bcnt      = (int*)(dinv + N_NODES);        // 128 ints
    int* bb        = bcnt + N_BKT;                  // 129 ints (padded to 132)
    int* csr_src   = bb + 132;
    unsigned int* u0 = (unsigned int*)(csr_src + N_EDGES);  // N*8 u32 (3.2 MB), 16B-aligned
    unsigned int* u1 = u0 + 8 * N_NODES;            // N*8 u32
    float* h1T     = (float*)(u1 + 8 * N_NODES);    // 64 * N floats (25.6 MB)
    unsigned int* bdata = (unsigned int*)h1T;       // 13.6 MB, dead before k_mlp1 writes h1T

    k_init<<<1, 128, 0, stream>>>(bcnt);
    k_bucket<<<BKT_NB, 256, 0, stream>>>(src, dst, bcnt, bdata);
    k_bscan<<<1, 128, 0, stream>>>(bcnt, bb);
    k_csr<<<2 * N_BKT, 512, 0, stream>>>(bdata, bcnt, bb, count, row_start, dinv, csr_src);
    k_mlp1<<<MLP1_NB, 256, 0, stream>>>(x, W1, b1, h1T);
    k_mlp2<<<SCAN_NB, 256, 0, stream>>>(h1T, W2, b2, W3, b3, Wc1, dinv, u0);

    unsigned int* ucur = u0;
    unsigned int* unxt = u1;
    for (int j = 0; j < 10; ++j) {
        const float* bias = (j < 5) ? bc1 : (bg + (long)(j - 5) * 16);
        if (j < 9) {
            const float* Wn = (j < 4) ? Wc1 : (Wg + (long)(j - 4) * 256);
            k_agg<<<6250, 256, 0, stream>>>(ucur, row_start, count, csr_src, dinv,
                                            bias, Wn, nullptr, unxt, nullptr, 0);
            unsigned int* tmp = ucur; ucur = unxt; unxt = tmp;
        } else {
            k_agg<<<6250, 256, 0, stream>>>(ucur, row_start, count, csr_src, dinv,
                                            bias, Wcls, bcls, nullptr, out, 1);
        }
    }
}

// Round 14
// 755.566 us; speedup vs baseline: 1.2487x; 1.0419x over previous
//
#include <hip/hip_runtime.h>
#include <hip/hip_fp16.h>
#include <math.h>

#define N_NODES 100000
#define N_EDGES 3200000
#define SCAN_NB ((N_NODES + 255) / 256)   // 391

// Two-phase CSR build: 128 dst-range buckets, LDS-resident CSR assembly.
#define N_BKT 128
#define NPB 782                           // nodes per bucket (128*782 = 100096 >= N)
#define HALF_NPB 391
#define BKT_CHUNK 2000
#define BKT_NB (N_EDGES / BKT_CHUNK)      // 1600 blocks
#define BKT_LDS_CAP 64                    // per-bucket LDS staging (mean 15.6, P(ovfl)~1e-18)
#define BUCKET_CAP 26624                  // per-bucket region (mean 25000, +10 sigma)
#define SLICE_CAP 14336                   // LDS csr slice (mean 12512, +16 sigma)

// MLP pass A tiling: 128-node tile, k staged in 4 chunks of <=33.
// FROZEN: 256 threads / 32 accumulators / wave-uniform half (t>>7). Two
// attempts to reshape this loop (512t R6, 64-tile R12) both broke codegen
// (VGPR blowup / per-lane W addressing) and ran 3.5x slower. Do not touch.
#define TILE_NODES 128
#define KCH 33
#define MLP1_NB ((N_NODES + TILE_NODES - 1) / TILE_NODES)   // 782

__device__ __forceinline__ unsigned int pack2(float a, float b) {
    __half2 h = __floats2half2_rn(a, b);
    return *reinterpret_cast<unsigned int*>(&h);
}
__device__ __forceinline__ float2 unpack2(unsigned int u) {
    __half2 h = *reinterpret_cast<__half2*>(&u);
    return __half22float2(h);
}

// ---------------- CSR build ----------------

__global__ void k_init(int* __restrict__ bcnt) {
    int i = threadIdx.x;
    if (i < N_BKT) bcnt[i] = 0;
}

// Phase 1: single coalesced pass over edges, pure bucketing (no global atomics).
// pack = (dst_local << 17) | src (dloc < 782 -> 10 bits, src < 100000 -> 17 bits).
// Flush: 4 buckets per wave-iteration (lane<15:4> = bucket, lane<3:0> = entry)
// -> all 64 lanes active (the old one-bucket-per-iteration flush idled 48/64).
__global__ __launch_bounds__(256) void k_bucket(
        const int* __restrict__ src, const int* __restrict__ dst,
        int* __restrict__ bcnt,
        unsigned int* __restrict__ bdata) {
    __shared__ unsigned int buf[N_BKT * BKT_LDS_CAP];   // 32768 B
    __shared__ int lcnt[N_BKT];
    __shared__ int gbase[N_BKT];
    const int t = threadIdx.x;
    if (t < N_BKT) lcnt[t] = 0;
    __syncthreads();

    const int e0 = blockIdx.x * BKT_CHUNK;
    for (int e = e0 + t; e < e0 + BKT_CHUNK; e += 256) {
        int d = __builtin_nontemporal_load(&dst[e]);
        int s = __builtin_nontemporal_load(&src[e]);
        int b = d / NPB;                              // magic-mul (const divisor)
        int dloc = d - b * NPB;
        unsigned int pack = ((unsigned int)dloc << 17) | (unsigned int)s;
        int p = atomicAdd(&lcnt[b], 1);               // LDS atomic
        if (p < BKT_LDS_CAP)                          // defensive clamp (never expected)
            buf[b * BKT_LDS_CAP + p] = pack;
    }
    __syncthreads();
    if (t < N_BKT) {
        int n = min(lcnt[t], BKT_LDS_CAP);
        lcnt[t] = n;
        gbase[t] = atomicAdd(&bcnt[t], n);
    }
    __syncthreads();
    const int wv = t >> 6, ln = t & 63;
    const int sub = ln >> 4;                          // bucket-within-quad 0..3
    const int el = ln & 15;                           // entry lane 0..15
#pragma unroll
    for (int it = 0; it < 8; ++it) {
        int b = wv * 32 + it * 4 + sub;
        int n = lcnt[b];
        unsigned int* outp = bdata + (size_t)b * BUCKET_CAP + gbase[b];
        for (int i = el; i < n; i += 16)
            __builtin_nontemporal_store(buf[b * BKT_LDS_CAP + i], &outp[i]);
    }
}

// Phase 2: LDS-resident CSR assembly + per-bucket degree derivation.
// k_bscan is FUSED: wave 0 computes bb_b = sum_{i<b} bcnt[i] via a masked
// 128-element wave reduce (removes a launch + the bb buffer).
__global__ __launch_bounds__(512) void k_csr(
        const unsigned int* __restrict__ bdata,
        const int* __restrict__ bcnt,
        int* __restrict__ count,
        int* __restrict__ row_start,
        float* __restrict__ dinv,
        int* __restrict__ csr_src) {
    __shared__ int lhist[NPB];
    __shared__ int lrs[NPB];
    __shared__ int lcsr[SLICE_CAP];     // total LDS 63600 B
    __shared__ int bb_s;
    const int b = blockIdx.x >> 1;
    const int half = blockIdx.x & 1;
    const int t = threadIdx.x;
    const int total = bcnt[b];
    const unsigned int* data = bdata + (size_t)b * BUCKET_CAP;

    if (t < 64) {   // fused bucket-prefix: bb_b = sum of bcnt[i] for i < b
        int c0 = (t < b) ? bcnt[t] : 0;
        int c1 = (t + 64 < b) ? bcnt[t + 64] : 0;
        int s = c0 + c1;
#pragma unroll
        for (int off = 1; off < 64; off <<= 1)
            s += __shfl_xor(s, off, 64);
        if (t == 0) bb_s = s;
    }
    for (int i = t; i < NPB; i += 512) lhist[i] = 0;
    __syncthreads();
    const int bb_b = bb_s;
    for (int i = t; i < total; i += 512) {
        unsigned int pack = __builtin_nontemporal_load(&data[i]);
        atomicAdd(&lhist[pack >> 17], 1);             // no-return LDS atomic
    }
    __syncthreads();
    // exclusive scan lhist -> lrs (wave 0: 13 elems/lane + shfl_up wave scan)
    if (t < 64) {
        int loc[13];
        int s = 0;
#pragma unroll
        for (int k = 0; k < 13; ++k) {
            int idx = t * 13 + k;
            int v = (idx < NPB) ? lhist[idx] : 0;
            loc[k] = v; s += v;
        }
        int run = s;
#pragma unroll
        for (int off = 1; off < 64; off <<= 1) {
            int o = __shfl_up(run, off, 64);
            if (t >= off) run += o;
        }
        int excl = run - s;
#pragma unroll
        for (int k = 0; k < 13; ++k) {
            int idx = t * 13 + k;
            if (idx < NPB) lrs[idx] = excl;
            excl += loc[k];
        }
    }
    __syncthreads();
    // per-node outputs for this half (coalesced)
    const int node_lo = b * NPB + half * HALF_NPB;
    int node_hi = b * NPB + (half ? NPB : HALF_NPB);
    if (node_hi > N_NODES) node_hi = N_NODES;
    const int nn = node_hi - node_lo;
    for (int i = t; i < nn; i += 512) {
        int dloc = half * HALF_NPB + i;
        int c = lhist[dloc];
        count[node_lo + i] = c;
        row_start[node_lo + i] = bb_b + lrs[dloc];
        dinv[node_lo + i] = 1.0f / sqrtf((float)(c + 1));   // deg incl self-loop
    }
    const int slice_off = lrs[half * HALF_NPB];
    const int slice_len = half ? (total - slice_off) : lrs[HALF_NPB];
    __syncthreads();   // lhist reads done -> safe to reuse as cursors
    const int dlo = half * HALF_NPB;
    const int dhi = dlo + HALF_NPB;
    for (int i = t; i < HALF_NPB; i += 512)
        lhist[dlo + i] = lrs[dlo + i] - slice_off;    // slice-local cursors
    __syncthreads();
    for (int i = t; i < total; i += 512) {
        unsigned int pack = __builtin_nontemporal_load(&data[i]);
        int dloc = (int)(pack >> 17);
        if (dloc >= dlo && dloc < dhi) {
            int p = atomicAdd(&lhist[dloc], 1);
            if (p < SLICE_CAP)                        // defensive clamp (never expected)
                lcsr[p] = (int)(pack & 0x1FFFFu);
        }
    }
    __syncthreads();
    const int gb = bb_b + slice_off;
    for (int i = t; i < slice_len; i += 512)
        __builtin_nontemporal_store(lcsr[i], &csr_src[gb + i]);
}

// ---------------- MLP pass A: layer 1 (131 -> 64) ----------------
// Proven 256-thread / 32-accumulator form (67 us, VGPR 24). Thread half (t>>7,
// wave-uniform) owns 32 of 64 outputs. Output feature-major h1T, coalesced.

__global__ __launch_bounds__(256) void k_mlp1(
        const float* __restrict__ x,
        const float* __restrict__ W1, const float* __restrict__ b1,
        float* __restrict__ h1T) {
    __shared__ float xs[TILE_NODES * KCH];   // 16896 B
    const int t = threadIdx.x;
    const int nl = t & 127;
    const int half_u = __builtin_amdgcn_readfirstlane(t >> 7);  // wave-uniform
    const int nbase = blockIdx.x * TILE_NODES;
    const int node = nbase + nl;

    float a[32];
#pragma unroll
    for (int j = 0; j < 32; ++j) a[j] = b1[half_u * 32 + j];

    for (int kc = 0; kc < 4; ++kc) {
        const int k0 = kc * KCH;
        const int len = (k0 + KCH <= 131) ? KCH : (131 - k0);   // 33,33,33,32
        __syncthreads();
        for (int i = t; i < TILE_NODES * KCH; i += 256) {
            int r = i / KCH;
            int c = i - r * KCH;
            int gr = nbase + r;
            xs[i] = (c < len && gr < N_NODES) ? x[(long)gr * 131 + k0 + c] : 0.0f;
        }
        __syncthreads();
        const float* myrow = xs + nl * KCH;
        for (int kk = 0; kk < len; ++kk) {
            float xk = myrow[kk];
            const float* wr = W1 + (k0 + kk) * 64 + half_u * 32;   // uniform -> s_load
#pragma unroll
            for (int j = 0; j < 32; ++j) a[j] += xk * wr[j];
        }
    }

    if (node < N_NODES) {
#pragma unroll
        for (int j = 0; j < 32; ++j)
            h1T[(half_u * 32 + j) * N_NODES + node] = tanhf(a[j]);
    }
}

// ---------------- MLP pass B: 64 -> 32 -> 16 -> conv-fuse ----------------
// Writes fp16 unified layout u16[node*8 + j] (8 x half2 = 32 B per node row;
// u16 total = 3.2 MB -> fits each XCD's 4 MB L2).

__global__ __launch_bounds__(256) void k_mlp2(
        const float* __restrict__ h1T,
        const float* __restrict__ W2, const float* __restrict__ b2,
        const float* __restrict__ W3, const float* __restrict__ b3,
        const float* __restrict__ Wc1,
        const float* __restrict__ dinv,
        unsigned int* __restrict__ u16) {
    const int node = blockIdx.x * 256 + threadIdx.x;
    if (node >= N_NODES) return;

    float a2[32];
#pragma unroll
    for (int j = 0; j < 32; ++j) a2[j] = b2[j];
    for (int k = 0; k < 64; ++k) {
        float hk = h1T[k * N_NODES + node];           // coalesced
        const float* wr = W2 + k * 32;                // uniform -> s_load
#pragma unroll
        for (int j = 0; j < 32; ++j) a2[j] += hk * wr[j];
    }
#pragma unroll
    for (int j = 0; j < 32; ++j) a2[j] = tanhf(a2[j]);

    float a3[16];
#pragma unroll
    for (int j = 0; j < 16; ++j) a3[j] = b3[j];
#pragma unroll 4
    for (int k = 0; k < 32; ++k) {
        float hk = a2[k];
        const float* wr = W3 + k * 16;
#pragma unroll
        for (int j = 0; j < 16; ++j) a3[j] += hk * wr[j];
    }

    float dv = dinv[node];
    float uo[16];
#pragma unroll
    for (int j = 0; j < 16; ++j) uo[j] = 0.0f;
#pragma unroll 4
    for (int k = 0; k < 16; ++k) {
        float hk = a3[k];
        const float* wr = Wc1 + k * 16;
#pragma unroll
        for (int j = 0; j < 16; ++j) uo[j] += hk * wr[j];
    }
    uint4* p = reinterpret_cast<uint4*>(u16 + (size_t)node * 8);
    uint4 w0, w1;
    w0.x = pack2(uo[0] * dv,  uo[1] * dv);  w0.y = pack2(uo[2] * dv,  uo[3] * dv);
    w0.z = pack2(uo[4] * dv,  uo[5] * dv);  w0.w = pack2(uo[6] * dv,  uo[7] * dv);
    w1.x = pack2(uo[8] * dv,  uo[9] * dv);  w1.y = pack2(uo[10] * dv, uo[11] * dv);
    w1.z = pack2(uo[12] * dv, uo[13] * dv); w1.w = pack2(uo[14] * dv, uo[15] * dv);
    p[0] = w0; p[1] = w1;
}

// ---------------- Fused aggregation + tanh + 16x16 transform (or classifier) ----------------
// fp16 u rows (32 B). 4 nodes/wave, 16 lanes/node: q = lp&1 (16 B half-row),
// g = lp>>1 (8 edge subgroups). All csr words issued up-front for cmax <= 64
// (covers max degree at this size); gathers fully unrolled. ~58 us/launch =
// the divergent-gather concurrency floor (R4/R7/R10/R11 variants converge);
// the residual is compulsory cross-XCD u redistribution each layer. Frozen
// except the occupancy hint (VGPR 32 <= the 64-VGPR bound for 8 waves/EU).

__global__ __launch_bounds__(256, 8) void k_agg(
        const unsigned int* __restrict__ u,
        const int* __restrict__ row_start,
        const int* __restrict__ count,
        const int* __restrict__ csr_src,
        const float* __restrict__ dinv,
        const float* __restrict__ bias,
        const float* __restrict__ W,      // 16x16 (mode 0) or 16x2 Wcls (mode 1)
        const float* __restrict__ bcls,   // mode 1 only
        unsigned int* __restrict__ u_next,// mode 0 output (fp16 rows)
        float* __restrict__ out,          // mode 1 output (fp32)
        int mode) {
    const int wave = threadIdx.x >> 6;
    const int lane = threadIdx.x & 63;
    const int lp = lane & 15;
    const int q = lp & 1;                              // 16B half-row slot
    const int q8 = q * 8;
    const int g = lp >> 1;                             // edge subgroup 0..7
    const int nb = lane >> 4;                          // node sub-index 0..3
    const int node = blockIdx.x * 16 + wave * 4 + nb;  // 6250*16 = 100000

    const int rs = row_start[node];
    const int cnt = count[node];
    const float dv = dinv[node];
    int cmax = cnt;
    cmax = max(cmax, __shfl_xor(cmax, 16, 64));
    cmax = max(cmax, __shfl_xor(cmax, 32, 64));        // wave-uniform loop bound

    float acc[8] = {0.0f, 0.0f, 0.0f, 0.0f, 0.0f, 0.0f, 0.0f, 0.0f};

    if (cmax <= 64) {
        // ---- deep-MLP path: all csr words issued up-front, gathers unrolled ----
        int idx[4];
#pragma unroll
        for (int c = 0; c < 4; ++c) {
            idx[c] = 0;
            if (c * 16 < cnt)                          // group-uniform guard
                idx[c] = __builtin_nontemporal_load(
                    &csr_src[min(rs + c * 16 + lp, N_EDGES - 1)]);
        }
#pragma unroll
        for (int c = 0; c < 4; ++c) {
#pragma unroll
            for (int r = 0; r < 2; ++r) {
                int e = c * 16 + 8 * r + g;
                int s = __shfl(idx[c], (lane & 48) + 8 * r + g, 64);
                if (e < cnt) {
                    const uint4 uv = *reinterpret_cast<const uint4*>(u + (size_t)s * 8 + q * 4);
                    float2 f0 = unpack2(uv.x), f1 = unpack2(uv.y);
                    float2 f2 = unpack2(uv.z), f3 = unpack2(uv.w);
                    acc[0] += f0.x; acc[1] += f0.y; acc[2] += f1.x; acc[3] += f1.y;
                    acc[4] += f2.x; acc[5] += f2.y; acc[6] += f3.x; acc[7] += f3.y;
                }
            }
        }
    } else {
        // ---- fallback (max degree > 64: never expected at this size) ----
        for (int base = 0; base < cmax; base += 16) {
            int idx0 = __builtin_nontemporal_load(
                &csr_src[min(rs + base + lp, N_EDGES - 1)]);
#pragma unroll
            for (int r = 0; r < 2; ++r) {
                int e = base + 8 * r + g;
                int s = __shfl(idx0, (lane & 48) + 8 * r + g, 64);
                if (e < cnt) {
                    const uint4 uv = *reinterpret_cast<const uint4*>(u + (size_t)s * 8 + q * 4);
                    float2 f0 = unpack2(uv.x), f1 = unpack2(uv.y);
                    float2 f2 = unpack2(uv.z), f3 = unpack2(uv.w);
                    acc[0] += f0.x; acc[1] += f0.y; acc[2] += f1.x; acc[3] += f1.y;
                    acc[4] += f2.x; acc[5] += f2.y; acc[6] += f3.x; acc[7] += f3.y;
                }
            }
        }
    }

    // reduce over the 8 edge subgroups (lane bits 1..3)
#pragma unroll
    for (int c = 0; c < 8; ++c) {
        acc[c] += __shfl_xor(acc[c], 2, 64);
        acc[c] += __shfl_xor(acc[c], 4, 64);
        acc[c] += __shfl_xor(acc[c], 8, 64);
    }
    // self-loop (u already dinv[src]-scaled)
    {
        const uint4 uv = *reinterpret_cast<const uint4*>(u + (size_t)node * 8 + q * 4);
        float2 f0 = unpack2(uv.x), f1 = unpack2(uv.y);
        float2 f2 = unpack2(uv.z), f3 = unpack2(uv.w);
        acc[0] += f0.x; acc[1] += f0.y; acc[2] += f1.x; acc[3] += f1.y;
        acc[4] += f2.x; acc[5] += f2.y; acc[6] += f3.x; acc[7] += f3.y;
    }

    float hn[8];
#pragma unroll
    for (int c = 0; c < 8; ++c)
        hn[c] = tanhf(dv * acc[c] + bias[q8 + c]);

    if (mode == 0) {
        float o[8] = {0.0f, 0.0f, 0.0f, 0.0f, 0.0f, 0.0f, 0.0f, 0.0f};
#pragma unroll
        for (int k = 0; k < 16; ++k) {
            // feature k lives in component k&7 of lane (lane&48)+(k>>3)  (q=k>>3, g=0)
            float hk = __shfl(hn[k & 7], (lane & 48) + (k >> 3), 64);
            const float* wrow = W + k * 16 + q8;      // 1 KB table, L1-hot
#pragma unroll
            for (int j = 0; j < 8; ++j) o[j] += hk * wrow[j];
        }
        if (g == 0) {
            uint4 w4;
            w4.x = pack2(dv * o[0], dv * o[1]); w4.y = pack2(dv * o[2], dv * o[3]);
            w4.z = pack2(dv * o[4], dv * o[5]); w4.w = pack2(dv * o[6], dv * o[7]);
            *reinterpret_cast<uint4*>(u_next + (size_t)node * 8 + q * 4) = w4;
        }
    } else {
        float p0 = 0.0f, p1 = 0.0f;
        if (g == 0) {
            float4 h4a, h4b;
            h4a.x = hn[0]; h4a.y = hn[1]; h4a.z = hn[2]; h4a.w = hn[3];
            h4b.x = hn[4]; h4b.y = hn[5]; h4b.z = hn[6]; h4b.w = hn[7];
            float4* ho = reinterpret_cast<float4*>(out + 200000 + (size_t)node * 16 + q8);
            ho[0] = h4a; ho[1] = h4b;
#pragma unroll
            for (int c = 0; c < 8; ++c) {
                p0 += hn[c] * W[(q8 + c) * 2 + 0];
                p1 += hn[c] * W[(q8 + c) * 2 + 1];
            }
        }
        p0 += __shfl_xor(p0, 1, 64);  p1 += __shfl_xor(p1, 1, 64);   // combine q halves
        if (lp == 0) {
            out[(long)node * 2 + 0] = p0 + bcls[0];
            out[(long)node * 2 + 1] = p1 + bcls[1];
        }
    }
}

// ---------------- launch ----------------

extern "C" void kernel_launch(void* const* d_in, const int* in_sizes, int n_in,
                              void* d_out, int out_size, void* d_ws, size_t ws_size,
                              hipStream_t stream) {
    const float* x    = (const float*)d_in[0];
    const int*   ei   = (const int*)d_in[1];
    const float* W1   = (const float*)d_in[2];
    const float* b1   = (const float*)d_in[3];
    const float* W2   = (const float*)d_in[4];
    const float* b2   = (const float*)d_in[5];
    const float* W3   = (const float*)d_in[6];
    const float* b3   = (const float*)d_in[7];
    const float* Wc1  = (const float*)d_in[8];
    const float* bc1  = (const float*)d_in[9];
    const float* Wg   = (const float*)d_in[10];
    const float* bg   = (const float*)d_in[11];
    const float* Wcls = (const float*)d_in[12];
    const float* bcls = (const float*)d_in[13];
    float* out = (float*)d_out;

    const int* src = ei;
    const int* dst = ei + N_EDGES;

    int* count     = (int*)d_ws;
    int* row_start = count + N_NODES;
    float* dinv    = (float*)(row_start + N_NODES);
    int* bcnt      = (int*)(dinv + N_NODES);        // 128 ints (+4 pad)
    int* csr_src   = bcnt + 132;
    unsigned int* u0 = (unsigned int*)(csr_src + N_EDGES);  // N*8 u32 (3.2 MB), 16B-aligned
    unsigned int* u1 = u0 + 8 * N_NODES;            // N*8 u32
    float* h1T     = (float*)(u1 + 8 * N_NODES);    // 64 * N floats (25.6 MB)
    unsigned int* bdata = (unsigned int*)h1T;       // 13.6 MB, dead before k_mlp1 writes h1T

    k_init<<<1, 128, 0, stream>>>(bcnt);
    k_bucket<<<BKT_NB, 256, 0, stream>>>(src, dst, bcnt, bdata);
    k_csr<<<2 * N_BKT, 512, 0, stream>>>(bdata, bcnt, count, row_start, dinv, csr_src);
    k_mlp1<<<MLP1_NB, 256, 0, stream>>>(x, W1, b1, h1T);
    k_mlp2<<<SCAN_NB, 256, 0, stream>>>(h1T, W2, b2, W3, b3, Wc1, dinv, u0);

    unsigned int* ucur = u0;
    unsigned int* unxt = u1;
    for (int j = 0; j < 10; ++j) {
        const float* bias = (j < 5) ? bc1 : (bg + (long)(j - 5) * 16);
        if (j < 9) {
            const float* Wn = (j < 4) ? Wc1 : (Wg + (long)(j - 4) * 256);
            k_agg<<<6250, 256, 0, stream>>>(ucur, row_start, count, csr_src, dinv,
                                            bias, Wn, nullptr, unxt, nullptr, 0);
            unsigned int* tmp = ucur; ucur = unxt; unxt = tmp;
        } else {
            k_agg<<<6250, 256, 0, stream>>>(ucur, row_start, count, csr_src, dinv,
                                            bias, Wcls, bcls, nullptr, out, 1);
        }
    }
}